// Round 5
// baseline (407.197 us; speedup 1.0000x reference)
//
#include <hip/hip_runtime.h>
#include <hip/hip_bf16.h>

typedef __bf16 bf16_t;
typedef bf16_t bf16x8 __attribute__((ext_vector_type(8)));
typedef float f32x4 __attribute__((ext_vector_type(4)));
typedef float f32x2 __attribute__((ext_vector_type(2)));

#define B_   128
#define T_   256
#define C_   64
#define H_   128
#define G_   512   // 4*H
#define BT   16    // batch rows per workgroup

#define K1 1.4426950408889634f   // log2(e)
#define K2 2.8853900817779268f   // 2*log2(e)

__device__ __forceinline__ f32x2 exp2v(f32x2 z) {
    f32x2 r; r.x = __builtin_amdgcn_exp2f(z.x); r.y = __builtin_amdgcn_exp2f(z.y); return r;
}
// 1/a, 1/b from ONE rcp: r=rcp(a*b); 1/a=r*b, 1/b=r*a. Safe: products < 1e21 << f32 max.
__device__ __forceinline__ f32x2 rcp_pair(f32x2 d) {
    const float q = __builtin_amdgcn_rcpf(d.x * d.y);
    f32x2 r; r.x = q * d.y; r.y = q * d.x; return r;
}

__global__ __launch_bounds__(512, 2) void lstm_fused(
    const float* __restrict__ x,     // [B,T,C]
    const float* __restrict__ w_ih,  // [C,4H]
    const float* __restrict__ w_hh,  // [C,4H,H]
    const float* __restrict__ b_ih,  // [C,4H]
    const float* __restrict__ b_hh,  // [C,4H]
    const float* __restrict__ w_fc,  // [C,H]
    const float* __restrict__ b_fc,  // [C]
    float* __restrict__ out)         // [B,C]
{
    const int cp   = blockIdx.x & 31;      // channel pair 0..31
    const int bt   = blockIdx.x >> 5;      // 0..7
    const int c0   = cp * 2;
    const int b0   = bt * BT;
    const int tid  = threadIdx.x;
    const int w    = tid >> 6;             // wave 0..7
    const int lane = tid & 63;
    const int l16  = lane & 15;
    const int lg   = lane >> 4;            // 0..3

    // h: [ch][kgrp16][row16][8] bf16, SINGLE buffer (reads/writes barrier-separated)
    __shared__ __align__(16) bf16_t h_lds[2][2048];   // 8 KB
    __shared__ __align__(16) float  x_lds[2][T_ * BT]; // 32 KB, [ch][t*16+row]

    for (int i = tid; i < 2048; i += 512) ((uint32_t*)h_lds)[i] = 0u;
    for (int i = tid; i < 2 * BT * T_; i += 512) {
        const int j = i >> 12, idx = i & 4095;
        const int bl = idx >> 8, t = idx & 255;
        x_lds[j][t * BT + bl] = x[(size_t)(b0 + bl) * (T_ * C_) + (size_t)t * C_ + c0 + j];
    }

    // ---- weights, pre-scaled into exp2 domain: i,f,o by -log2e; g by +2*log2e
    // wave w owns gate-cols n(q) = q*128 + w*16 + l16 for BOTH channels
    bf16x8 bw[2][4][4];        // [ch][gate][k-frag] -> AGPR-resident
    float  wih[2][4], bias[2][4];
    #pragma unroll
    for (int j = 0; j < 2; ++j) {
        const int c = c0 + j;
        #pragma unroll
        for (int q = 0; q < 4; ++q) {
            const float s = (q == 2) ? K2 : -K1;
            const int n = q * 128 + w * 16 + l16;
            wih[j][q]  = s * w_ih[c * G_ + n];
            bias[j][q] = s * (b_ih[c * G_ + n] + b_hh[c * G_ + n]);
            #pragma unroll
            for (int kk = 0; kk < 4; ++kk) {
                const int k0 = kk * 32 + lg * 8;
                const float4 wa = *(const float4*)&w_hh[((size_t)(c * G_ + n)) * H_ + k0];
                const float4 wb = *(const float4*)&w_hh[((size_t)(c * G_ + n)) * H_ + k0 + 4];
                bf16x8 g;
                g[0] = (bf16_t)(s * wa.x); g[1] = (bf16_t)(s * wa.y);
                g[2] = (bf16_t)(s * wa.z); g[3] = (bf16_t)(s * wa.w);
                g[4] = (bf16_t)(s * wb.x); g[5] = (bf16_t)(s * wb.y);
                g[6] = (bf16_t)(s * wb.z); g[7] = (bf16_t)(s * wb.w);
                bw[j][q][kk] = g;
            }
        }
    }

    f32x4 acc[2][4];           // gate accumulators, persist across half-steps
    float cst[2][4] = {{0.f,0.f,0.f,0.f},{0.f,0.f,0.f,0.f}};
    const f32x2 one2 = {1.f, 1.f};

    const int a_off = l16 * 8;
    const int wb_   = (w * 2 + (l16 >> 3)) * 128 + lg * 32 + (l16 & 7);

    // MFMA half: gates_j(t) = h_j(t) @ w_hh^T + x_j(t)*w_ih + b   (all pre-scaled)
    auto MF = [&](const int j, const int t) {
        const f32x4 xv = *(const f32x4*)&x_lds[j][t * BT + lg * 4]; // rows lg*4..+3
        #pragma unroll
        for (int q = 0; q < 4; ++q)
            #pragma unroll
            for (int r = 0; r < 4; ++r)
                acc[j][q][r] = fmaf(xv[r], wih[j][q], bias[j][q]);
        #pragma unroll
        for (int kk = 0; kk < 4; ++kk) {
            const bf16x8 a = *(const bf16x8*)&h_lds[j][(kk * 4 + lg) * 128 + a_off];
            #pragma unroll
            for (int q = 0; q < 4; ++q)
                acc[j][q] = __builtin_amdgcn_mfma_f32_16x16x32_bf16(a, bw[j][q][kk], acc[j][q], 0, 0, 0);
        }
    };

    // Activation half: acc_j -> h_j (written into single LDS buffer)
    auto ACT = [&](const int j) {
        #pragma unroll
        for (int p = 0; p < 2; ++p) {
            const f32x2 ei = exp2v(f32x2{acc[j][0][2*p], acc[j][0][2*p+1]});
            const f32x2 ef = exp2v(f32x2{acc[j][1][2*p], acc[j][1][2*p+1]});
            const f32x2 eg = exp2v(f32x2{acc[j][2][2*p], acc[j][2][2*p+1]});
            const f32x2 eo = exp2v(f32x2{acc[j][3][2*p], acc[j][3][2*p+1]});
            const f32x2 A2 = one2 + ei, D2 = one2 + ef, B2 = one2 + eg, O2 = one2 + eo;
            const f32x2 AB = A2 * B2;
            const f32x2 r1 = rcp_pair(D2 * AB);
            const f32x2 cs = {cst[j][2*p], cst[j][2*p+1]};
            const f32x2 cn = (D2 * (eg - one2) + cs * AB) * r1;
            cst[j][2*p] = cn.x; cst[j][2*p+1] = cn.y;
            f32x2 m2;
            m2.x = __builtin_amdgcn_fmed3f(K2 * cn.x, -24.f, 24.f);
            m2.y = __builtin_amdgcn_fmed3f(K2 * cn.y, -24.f, 24.f);
            const f32x2 ec = exp2v(m2);
            const f32x2 r2 = rcp_pair(O2 * (one2 + ec));
            const f32x2 hv = (ec - one2) * r2;           // sig(o)*tanh(cn)
            h_lds[j][wb_ + (2*p)   * 8] = (bf16_t)hv.x;
            h_lds[j][wb_ + (2*p+1) * 8] = (bf16_t)hv.y;
        }
    };

    // Software pipeline: ch0's MFMA co-issues with ch1's activation and vice versa.
    for (int t = 0; t < T_; ++t) {
        __syncthreads();         // h0(t) visible
        MF(0, t);                // MFMA pipe: gates0(t)
        if (t) ACT(1);           // VALU pipe: acc1(t-1) -> h1(t)   (independent of MF(0,t))
        __syncthreads();         // h1(t) visible
        MF(1, t);                // MFMA pipe: gates1(t)
        ACT(0);                  // VALU pipe: acc0(t) -> h0(t+1)
    }
    ACT(1);                      // acc1(T-1) -> h1(T)
    __syncthreads();

    // ---- epilogue: out[b][c] = dot(h_T[b,:], w_fc[c,:]) + b_fc[c]
    #pragma unroll
    for (int j = 0; j < 2; ++j) {
        const int c = c0 + j;
        #pragma unroll
        for (int rr = 0; rr < 2; ++rr) {
            const int row = w * 2 + rr;
            const int eaddr = (lane >> 2) * 128 + row * 8 + (lane & 3) * 2;
            const float h0 = (float)h_lds[j][eaddr];
            const float h1 = (float)h_lds[j][eaddr + 1];
            const float2 wf = *(const float2*)&w_fc[c * H_ + 2 * lane];
            float p = h0 * wf.x + h1 * wf.y;
            #pragma unroll
            for (int off = 32; off; off >>= 1) p += __shfl_xor(p, off);
            if (lane == 0) out[(size_t)(b0 + row) * C_ + c] = p + b_fc[c];
        }
    }
}

extern "C" void kernel_launch(void* const* d_in, const int* in_sizes, int n_in,
                              void* d_out, int out_size, void* d_ws, size_t ws_size,
                              hipStream_t stream) {
    const float* x    = (const float*)d_in[0];
    const float* w_ih = (const float*)d_in[1];
    const float* w_hh = (const float*)d_in[2];
    const float* b_ih = (const float*)d_in[3];
    const float* b_hh = (const float*)d_in[4];
    const float* w_fc = (const float*)d_in[5];
    const float* b_fc = (const float*)d_in[6];
    float* out = (float*)d_out;

    dim3 grid((C_ / 2) * (B_ / BT));   // 32 channel-pairs * 8 b-tiles = 256 WGs (1/CU)
    dim3 block(512);                   // 8 waves
    lstm_fused<<<grid, block, 0, stream>>>(x, w_ih, w_hh, b_ih, b_hh, w_fc, b_fc, out);
}

// Round 6
// 407.192 us; speedup vs baseline: 1.0000x; 1.0000x over previous
//
#include <hip/hip_runtime.h>
#include <hip/hip_bf16.h>

typedef __bf16 bf16_t;
typedef bf16_t bf16x8 __attribute__((ext_vector_type(8)));
typedef float f32x4 __attribute__((ext_vector_type(4)));
typedef float f32x2 __attribute__((ext_vector_type(2)));

#define B_   128
#define T_   256
#define C_   64
#define H_   128
#define G_   512   // 4*H
#define BT   32    // batch rows per workgroup = 2 streams x 16

#define K1 1.4426950408889634f   // log2(e)
#define K2 2.8853900817779268f   // 2*log2(e)

union AF { bf16x8 v; uint32_t w[4]; };

__device__ __forceinline__ uint32_t cvt_pk_bf16(float a, float b) {
    uint32_t r; asm("v_cvt_pk_bf16_f32 %0, %1, %2" : "=v"(r) : "v"(a), "v"(b)); return r;
}
__device__ __forceinline__ f32x2 exp2v(f32x2 z) {
    f32x2 r; r.x = __builtin_amdgcn_exp2f(z.x); r.y = __builtin_amdgcn_exp2f(z.y); return r;
}
// 1/a, 1/b from ONE rcp: q=rcp(a*b); 1/a=q*b, 1/b=q*a. Products bounded < 1e29 (see clamp).
__device__ __forceinline__ f32x2 rcp_pair(f32x2 d) {
    const float q = __builtin_amdgcn_rcpf(d.x * d.y);
    f32x2 r; r.x = q * d.y; r.y = q * d.x; return r;
}

__global__ __launch_bounds__(512, 2) void lstm_fused(
    const float* __restrict__ x,     // [B,T,C]
    const float* __restrict__ w_ih,  // [C,4H]
    const float* __restrict__ w_hh,  // [C,4H,H]
    const float* __restrict__ b_ih,  // [C,4H]
    const float* __restrict__ b_hh,  // [C,4H]
    const float* __restrict__ w_fc,  // [C,H]
    const float* __restrict__ b_fc,  // [C]
    float* __restrict__ out)         // [B,C]
{
    const int c    = blockIdx.x & (C_ - 1);
    const int bt   = blockIdx.x >> 6;      // 0..3
    const int b0   = bt * BT;
    const int tid  = threadIdx.x;
    const int w    = tid >> 6;             // wave 0..7
    const int lane = tid & 63;
    const int l16  = lane & 15;
    const int lg   = lane >> 4;            // 0..3
    const bool lg0 = (lg == 0);

    // h: per-stream [kgrp16][row16][8] bf16, single buffer (barrier-separated R/W)
    __shared__ __align__(16) bf16_t h_lds[2][2048];    // 8 KB
    __shared__ __align__(16) float  x_lds[T_ * BT];    // [t][row0..31], 32 KB

    for (int i = tid; i < 2048; i += 512) ((uint32_t*)h_lds)[i] = 0u;
    for (int i = tid; i < BT * T_; i += 512) {
        const int row = i >> 8, t = i & 255;
        x_lds[t * BT + row] = x[(size_t)(b0 + row) * (T_ * C_) + (size_t)t * C_ + c];
    }

    // ---- weights, pre-scaled into exp2 domain (i,f,o: -log2e; g: +2log2e).
    // Wave w owns gate-cols n(q)=q*128+w*16+l16; SHARED by both streams.
    bf16x8 bw[4][4];           // [gate][k-frag] -> AGPR-resident
    AF     augb[4];            // (wih_h, wih_l, wih_h, bias_h, bias_l, 0,0,0)
    #pragma unroll
    for (int q = 0; q < 4; ++q) {
        const float s = (q == 2) ? K2 : -K1;
        const int n = q * 128 + w * 16 + l16;
        #pragma unroll
        for (int kk = 0; kk < 4; ++kk) {
            const int k0 = kk * 32 + lg * 8;
            const float4 wa = *(const float4*)&w_hh[((size_t)(c * G_ + n)) * H_ + k0];
            const float4 wb = *(const float4*)&w_hh[((size_t)(c * G_ + n)) * H_ + k0 + 4];
            bf16x8 g;
            g[0] = (bf16_t)(s * wa.x); g[1] = (bf16_t)(s * wa.y);
            g[2] = (bf16_t)(s * wa.z); g[3] = (bf16_t)(s * wa.w);
            g[4] = (bf16_t)(s * wb.x); g[5] = (bf16_t)(s * wb.y);
            g[6] = (bf16_t)(s * wb.z); g[7] = (bf16_t)(s * wb.w);
            bw[q][kk] = g;
        }
        const float wv = s * w_ih[c * G_ + n];
        const bf16_t wh = (bf16_t)wv;
        const bf16_t wl = (bf16_t)(wv - (float)wh);
        const float bb = s * (b_ih[c * G_ + n] + b_hh[c * G_ + n]);
        const bf16_t bh  = (bf16_t)bb;
        const bf16_t bl2 = (bf16_t)(bb - (float)bh);
        bf16x8 f;
        #pragma unroll
        for (int e = 0; e < 8; ++e) f[e] = (bf16_t)0.0f;
        if (lg0) { f[0] = wh; f[1] = wl; f[2] = wh; f[3] = bh; f[4] = bl2; }
        augb[q].v = f;
    }

    f32x4 acc[2][4];                       // [stream][gate]
    float cst[2][4] = {{0.f,0.f,0.f,0.f},{0.f,0.f,0.f,0.f}};
    const f32x4 zc = {0.f, 0.f, 0.f, 0.f};
    const f32x2 one2 = {1.f, 1.f};

    const int a_off = l16 * 8;
    const int wb_   = (w * 2 + (l16 >> 3)) * 128 + lg * 32 + (l16 & 7);

    // MFMA half for stream s: gates(t) = h_s @ w_hh^T + x*w_ih + b (exp2-scaled)
    auto MF = [&](const int s, const int t) {
        const float xr = x_lds[t * BT + s * 16 + l16];
        const uint32_t p0 = cvt_pk_bf16(xr, xr);          // (xh,xh)
        const float xhf = __uint_as_float(p0 << 16);
        const uint32_t p1 = cvt_pk_bf16(xr - xhf, 1.0f);  // (xl,1)
        AF a4;
        a4.w[0] = lg0 ? p0 : 0u;
        a4.w[1] = lg0 ? p1 : 0u;
        a4.w[2] = lg0 ? 0x00003F80u : 0u;                 // (1,0)
        a4.w[3] = 0u;
        #pragma unroll
        for (int q = 0; q < 4; ++q)
            acc[s][q] = __builtin_amdgcn_mfma_f32_16x16x32_bf16(a4.v, augb[q].v, zc, 0, 0, 0);
        #pragma unroll
        for (int kk = 0; kk < 4; ++kk) {
            const bf16x8 a = *(const bf16x8*)&h_lds[s][(kk * 4 + lg) * 128 + a_off];
            #pragma unroll
            for (int q = 0; q < 4; ++q)
                acc[s][q] = __builtin_amdgcn_mfma_f32_16x16x32_bf16(a, bw[q][kk], acc[s][q], 0, 0, 0);
        }
    };

    // Activation half for stream s: acc -> h_s
    auto ACT = [&](const int s) {
        #pragma unroll
        for (int p = 0; p < 2; ++p) {
            const f32x2 ei = exp2v(f32x2{acc[s][0][2*p], acc[s][0][2*p+1]});
            const f32x2 ef = exp2v(f32x2{acc[s][1][2*p], acc[s][1][2*p+1]});
            const f32x2 eg = exp2v(f32x2{acc[s][2][2*p], acc[s][2][2*p+1]});
            const f32x2 eo = exp2v(f32x2{acc[s][3][2*p], acc[s][3][2*p+1]});
            const f32x2 A2 = one2 + ei, D2 = one2 + ef, B2 = one2 + eg, O2 = one2 + eo;
            const f32x2 AB = A2 * B2;
            const f32x2 r1 = rcp_pair(D2 * AB);
            const f32x2 cs = {cst[s][2*p], cst[s][2*p+1]};
            const f32x2 cn = (D2 * (eg - one2) + cs * AB) * r1;
            cst[s][2*p] = cn.x; cst[s][2*p+1] = cn.y;
            f32x2 m2;
            m2.x = __builtin_amdgcn_fmed3f(K2 * cn.x, -24.f, 24.f);
            m2.y = __builtin_amdgcn_fmed3f(K2 * cn.y, -24.f, 24.f);
            const f32x2 ec = exp2v(m2);
            const f32x2 r2 = rcp_pair(O2 * (one2 + ec));
            const f32x2 hv = (ec - one2) * r2;            // sig(o)*tanh(cn)
            h_lds[s][wb_ + (2*p)   * 8] = (bf16_t)hv.x;
            h_lds[s][wb_ + (2*p+1) * 8] = (bf16_t)hv.y;
        }
    };

    __syncthreads();
    // prologue (t=0)
    MF(0, 0);
    __syncthreads();
    MF(1, 0);
    ACT(0);
    // steady state: MFMA of one stream co-issues with ACT of the other
    for (int t = 1; t < T_; ++t) {
        __syncthreads();        // h0(t) visible
        MF(0, t);
        ACT(1);                 // acc1(t-1) -> h1(t)  (independent of MF(0,t))
        __syncthreads();        // h1(t) visible
        MF(1, t);
        ACT(0);                 // acc0(t) -> h0(t+1)
    }
    ACT(1);                     // acc1(T-1) -> h1(T)
    __syncthreads();

    // ---- epilogue: out[b][c] = dot(h_T[b,:], w_fc[c,:]) + b_fc[c]
    #pragma unroll
    for (int rr = 0; rr < 4; ++rr) {
        const int row = w * 4 + rr;        // 0..31
        const int s   = row >> 4;
        const int lr  = row & 15;
        const int eaddr = (lane >> 2) * 128 + lr * 8 + (lane & 3) * 2;  // k=2*lane
        const float h0 = (float)h_lds[s][eaddr];
        const float h1 = (float)h_lds[s][eaddr + 1];
        const float2 wf = *(const float2*)&w_fc[c * H_ + 2 * lane];
        float p = h0 * wf.x + h1 * wf.y;
        #pragma unroll
        for (int off = 32; off; off >>= 1) p += __shfl_xor(p, off);
        if (lane == 0) out[(size_t)(b0 + row) * C_ + c] = p + b_fc[c];
    }
}

extern "C" void kernel_launch(void* const* d_in, const int* in_sizes, int n_in,
                              void* d_out, int out_size, void* d_ws, size_t ws_size,
                              hipStream_t stream) {
    const float* x    = (const float*)d_in[0];
    const float* w_ih = (const float*)d_in[1];
    const float* w_hh = (const float*)d_in[2];
    const float* b_ih = (const float*)d_in[3];
    const float* b_hh = (const float*)d_in[4];
    const float* w_fc = (const float*)d_in[5];
    const float* b_fc = (const float*)d_in[6];
    float* out = (float*)d_out;

    dim3 grid(C_ * (B_ / BT));   // 64 ch * 4 b-tiles = 256 WGs (1/CU)
    dim3 block(512);             // 8 waves
    lstm_fused<<<grid, block, 0, stream>>>(x, w_ih, w_hh, b_ih, b_hh, w_fc, b_fc, out);
}

// Round 7
// 392.845 us; speedup vs baseline: 1.0365x; 1.0365x over previous
//
#include <hip/hip_runtime.h>
#include <hip/hip_bf16.h>

typedef __bf16 bf16_t;
typedef bf16_t bf16x8 __attribute__((ext_vector_type(8)));
typedef float f32x4 __attribute__((ext_vector_type(4)));
typedef float f32x2 __attribute__((ext_vector_type(2)));

#define B_   128
#define T_   256
#define C_   64
#define H_   128
#define G_   512   // 4*H
#define RT   16    // batch rows per workgroup

#define K1 1.4426950408889634f   // log2(e)
#define K2 2.8853900817779268f   // 2*log2(e)

__device__ __forceinline__ uint32_t cvt_pk_bf16(float a, float b) {
    uint32_t r; asm("v_cvt_pk_bf16_f32 %0, %1, %2" : "=v"(r) : "v"(a), "v"(b)); return r;
}
__device__ __forceinline__ f32x2 exp2v(f32x2 z) {
    f32x2 r; r.x = __builtin_amdgcn_exp2f(z.x); r.y = __builtin_amdgcn_exp2f(z.y); return r;
}
// {1/d.x, 1/d.y} with ONE v_rcp: q=rcp(dx*dy); validated on this data in rounds 5-6.
__device__ __forceinline__ f32x2 rcp_pair(f32x2 d) {
    const float q = __builtin_amdgcn_rcpf(d.x * d.y);
    f32x2 r; r.x = q * d.y; r.y = q * d.x; return r;
}

// 8 waves: group g = w>>2 owns channel c0+g. Group phases offset by 1 period:
// period p: group g does MF (gates via MFMA) if ((p^g)&1)==0, else ACT (trans).
// => every SIMD always has 1 MFMA-phase wave + 1 trans-phase wave.
__global__ __launch_bounds__(512, 2) void lstm_fused(
    const float* __restrict__ x,     // [B,T,C]
    const float* __restrict__ w_ih,  // [C,4H]
    const float* __restrict__ w_hh,  // [C,4H,H]
    const float* __restrict__ b_ih,  // [C,4H]
    const float* __restrict__ b_hh,  // [C,4H]
    const float* __restrict__ w_fc,  // [C,H]
    const float* __restrict__ b_fc,  // [C]
    float* __restrict__ out)         // [B,C]
{
    const int cp   = blockIdx.x & 31;      // channel pair 0..31
    const int bt   = blockIdx.x >> 5;      // 0..7
    const int c0   = cp * 2;
    const int b0   = bt * RT;
    const int tid  = threadIdx.x;
    const int w    = tid >> 6;             // wave 0..7
    const int g    = w >> 2;               // channel group 0/1
    const int ws   = w & 3;                // sub-wave 0..3 (col block)
    const int lane = tid & 63;
    const int l16  = lane & 15;
    const int lg   = lane >> 4;            // 0..3

    // h per channel: [kgrp(16)][row(16)][8] bf16, single buffer (barrier-separated R/W)
    __shared__ __align__(16) bf16_t h_lds[2][2048];     // 8 KB
    __shared__ __align__(16) float  x_lds[2][T_ * RT];  // 32 KB, [ch][t*16+row]
    __shared__ float btab[2][4][4][2][16];              // [ch][q][ws][u][l16], 4 KB
    __shared__ float wtab[2][4][4][2][16];              // 4 KB

    for (int i = tid; i < 2048; i += 512) ((uint32_t*)h_lds)[i] = 0u;
    for (int i = tid; i < 2 * T_ * RT; i += 512) {
        const int ch = i >> 12, rem = i & 4095;
        const int t = rem >> 4, row = rem & 15;
        x_lds[ch][t * RT + row] = x[(size_t)(b0 + row) * (T_ * C_) + (size_t)t * C_ + c0 + ch];
    }
    for (int i = tid; i < 2 * 4 * 4 * 2 * 16; i += 512) {
        const int l  = i & 15;
        const int u  = (i >> 4) & 1;
        const int wsub = (i >> 5) & 3;
        const int q  = (i >> 7) & 3;
        const int ch = (i >> 9) & 1;
        const float s = (q == 2) ? K2 : -K1;
        const int n  = q * 128 + wsub * 32 + 2 * l + u;
        const int cc = c0 + ch;
        btab[ch][q][wsub][u][l] = s * (b_ih[cc * G_ + n] + b_hh[cc * G_ + n]);
        wtab[ch][q][wsub][u][l] = s * w_ih[cc * G_ + n];
    }

    // ---- weights, pre-scaled into exp2 domain (i,f,o: -log2e; g: +2log2e).
    // Wave owns gate-cols n(q,u) = q*128 + ws*32 + 2*l16 + u of channel c0+g.
    bf16x8 bw[4][2][4];        // [gate][u][k-frag] = 128 regs -> AGPR-resident
    #pragma unroll
    for (int q = 0; q < 4; ++q) {
        const float s = (q == 2) ? K2 : -K1;
        #pragma unroll
        for (int u = 0; u < 2; ++u) {
            const int n = q * 128 + ws * 32 + 2 * l16 + u;
            #pragma unroll
            for (int kk = 0; kk < 4; ++kk) {
                const int k0 = kk * 32 + lg * 8;
                const float4 wa = *(const float4*)&w_hh[((size_t)((c0 + g) * G_ + n)) * H_ + k0];
                const float4 wb = *(const float4*)&w_hh[((size_t)((c0 + g) * G_ + n)) * H_ + k0 + 4];
                bf16x8 f;
                f[0] = (bf16_t)(s * wa.x); f[1] = (bf16_t)(s * wa.y);
                f[2] = (bf16_t)(s * wa.z); f[3] = (bf16_t)(s * wa.w);
                f[4] = (bf16_t)(s * wb.x); f[5] = (bf16_t)(s * wb.y);
                f[6] = (bf16_t)(s * wb.z); f[7] = (bf16_t)(s * wb.w);
                bw[q][u][kk] = f;
            }
        }
    }

    f32x4 acc[4][2];                 // [gate][u], persists MF-period -> ACT-period
    float cst[2][4] = {{0.f,0.f,0.f,0.f},{0.f,0.f,0.f,0.f}};  // [u][r]
    const f32x2 one2 = {1.f, 1.f};

    const int a_base = l16 * 8;      // A-frag: row=l16, + (kk*4+lg)*128
    // packed h-write: cols (2*l16, 2*l16+1), rows lg*4+r
    const int wp = ((ws * 4 + (l16 >> 2)) * 16 + lg * 4) * 8 + 2 * (l16 & 3);

    auto MF = [&](const int t) {
        const f32x4 xv = *(const f32x4*)&x_lds[g][t * RT + lg * 4];  // rows lg*4..+3
        #pragma unroll
        for (int q = 0; q < 4; ++q)
            #pragma unroll
            for (int u = 0; u < 2; ++u) {
                const float bb = btab[g][q][ws][u][l16];
                const float wi = wtab[g][q][ws][u][l16];
                #pragma unroll
                for (int r = 0; r < 4; ++r) acc[q][u][r] = fmaf(xv[r], wi, bb);
            }
        #pragma unroll
        for (int kk = 0; kk < 4; ++kk) {
            const bf16x8 a = *(const bf16x8*)&h_lds[g][(kk * 4 + lg) * 128 + a_base];
            #pragma unroll
            for (int q = 0; q < 4; ++q)
                #pragma unroll
                for (int u = 0; u < 2; ++u)
                    acc[q][u] = __builtin_amdgcn_mfma_f32_16x16x32_bf16(a, bw[q][u][kk], acc[q][u], 0, 0, 0);
        }
    };

    auto ACT = [&]() {
        #pragma unroll
        for (int r = 0; r < 4; ++r) {   // pair across u: cols 2*l16 (x) and 2*l16+1 (y)
            const f32x2 ei = exp2v(f32x2{acc[0][0][r], acc[0][1][r]});
            const f32x2 ef = exp2v(f32x2{acc[1][0][r], acc[1][1][r]});
            const f32x2 eg = exp2v(f32x2{acc[2][0][r], acc[2][1][r]});
            const f32x2 eo = exp2v(f32x2{acc[3][0][r], acc[3][1][r]});
            const f32x2 A2 = one2 + ei, D2 = one2 + ef, B2 = one2 + eg, O2 = one2 + eo;
            const f32x2 AB = A2 * B2;
            const f32x2 r1 = rcp_pair(D2 * AB);
            const f32x2 cs = {cst[0][r], cst[1][r]};
            const f32x2 cn = (D2 * (eg - one2) + cs * AB) * r1;  // sig(f)c + sig(i)tanh(g)
            cst[0][r] = cn.x; cst[1][r] = cn.y;
            f32x2 m2;
            m2.x = __builtin_amdgcn_fmed3f(K2 * cn.x, -24.f, 24.f);
            m2.y = __builtin_amdgcn_fmed3f(K2 * cn.y, -24.f, 24.f);
            const f32x2 ec = exp2v(m2);
            const f32x2 r2 = rcp_pair(O2 * (one2 + ec));
            const f32x2 hv = (ec - one2) * r2;                   // sig(o)*tanh(cn)
            *(uint32_t*)&h_lds[g][wp + r * 8] = cvt_pk_bf16(hv.x, hv.y);
        }
    };

    __syncthreads();

    // 512 periods; group g: MF at p==g (mod 2) advancing t=p>>1, ACT one period later.
    for (int p = 0; p < 2 * T_; ++p) {
        if (((p ^ g) & 1) == 0) {
            MF(p >> 1);
        } else if (p > 1 || g == 0) {
            ACT();
        }
        __syncthreads();
    }
    if (g == 1) ACT();               // finish t=255 for channel group 1
    __syncthreads();

    // ---- epilogue: out[b][c] = dot(h_T[b,:], w_fc[c,:]) + b_fc[c]
    #pragma unroll
    for (int rr = 0; rr < 4; ++rr) {
        const int row = ws * 4 + rr;
        const int ea  = (lane >> 2) * 128 + row * 8 + (lane & 3) * 2;  // k = 2*lane, +1
        const float h0 = (float)h_lds[g][ea];
        const float h1 = (float)h_lds[g][ea + 1];
        const float2 wf = *(const float2*)&w_fc[(c0 + g) * H_ + 2 * lane];
        float pr = h0 * wf.x + h1 * wf.y;
        #pragma unroll
        for (int off = 32; off; off >>= 1) pr += __shfl_xor(pr, off);
        if (lane == 0) out[(size_t)(b0 + row) * C_ + c0 + g] = pr + b_fc[c0 + g];
    }
}

extern "C" void kernel_launch(void* const* d_in, const int* in_sizes, int n_in,
                              void* d_out, int out_size, void* d_ws, size_t ws_size,
                              hipStream_t stream) {
    const float* x    = (const float*)d_in[0];
    const float* w_ih = (const float*)d_in[1];
    const float* w_hh = (const float*)d_in[2];
    const float* b_ih = (const float*)d_in[3];
    const float* b_hh = (const float*)d_in[4];
    const float* w_fc = (const float*)d_in[5];
    const float* b_fc = (const float*)d_in[6];
    float* out = (float*)d_out;

    dim3 grid((C_ / 2) * (B_ / RT));   // 32 ch-pairs * 8 b-tiles = 256 WGs (1/CU)
    dim3 block(512);                   // 8 waves = 2 anti-phased groups of 4
    lstm_fused<<<grid, block, 0, stream>>>(x, w_ih, w_hh, b_ih, b_hh, w_fc, b_fc, out);
}

// Round 8
// 354.982 us; speedup vs baseline: 1.1471x; 1.1067x over previous
//
#include <hip/hip_runtime.h>
#include <hip/hip_bf16.h>

typedef __bf16 bf16_t;
typedef bf16_t bf16x8 __attribute__((ext_vector_type(8)));
typedef float f32x4 __attribute__((ext_vector_type(4)));
typedef float f32x2 __attribute__((ext_vector_type(2)));

#define B_   128
#define T_   256
#define C_   64
#define H_   128
#define G_   512   // 4*H
#define BT   16    // batch rows per workgroup
#define HBUF 2048  // bf16 elems per h buffer: 16 kgrp * 16 rows * 8

#define K1 1.4426950408889634f   // log2(e)
#define K2 2.8853900817779268f   // 2*log2(e)

union AF { bf16x8 v; uint32_t w[4]; };

__device__ __forceinline__ uint32_t cvt_pk_bf16(float a, float b) {
    uint32_t r; asm("v_cvt_pk_bf16_f32 %0, %1, %2" : "=v"(r) : "v"(a), "v"(b)); return r;
}
__device__ __forceinline__ f32x2 exp2v(f32x2 z) {
    f32x2 r; r.x = __builtin_amdgcn_exp2f(z.x); r.y = __builtin_amdgcn_exp2f(z.y); return r;
}
// {1/d.x, 1/d.y} with ONE v_rcp: q = rcp(dx*dy); 1/dx = q*dy, 1/dy = q*dx.
// Range-safe on this data (validated R5-R7, absmax 9.8e-4): products < 1e31 with ec clamped.
__device__ __forceinline__ f32x2 rcp_pair(f32x2 d) {
    const float q = __builtin_amdgcn_rcpf(d.x * d.y);
    f32x2 r; r.x = q * d.y; r.y = q * d.x; return r;
}

__global__ __launch_bounds__(512, 4) void lstm_fused(
    const float* __restrict__ x,     // [B,T,C]
    const float* __restrict__ w_ih,  // [C,4H]
    const float* __restrict__ w_hh,  // [C,4H,H]
    const float* __restrict__ b_ih,  // [C,4H]
    const float* __restrict__ b_hh,  // [C,4H]
    const float* __restrict__ w_fc,  // [C,H]
    const float* __restrict__ b_fc,  // [C]
    float* __restrict__ out)         // [B,C]
{
    const int c    = blockIdx.x & (C_ - 1);
    const int bt   = blockIdx.x >> 6;      // 0..7
    const int b0   = bt * BT;
    const int tid  = threadIdx.x;
    const int w    = tid >> 6;             // wave 0..7
    const int lane = tid & 63;
    const int l16  = lane & 15;
    const int lg   = lane >> 4;            // 0..3
    const bool lg0 = (lg == 0);

    // h layout: [buf][kgrp(16)][row(16)][e(8)] bf16 -> conflict-free b128 A reads
    __shared__ __align__(16) bf16_t h_lds[2 * HBUF];   // 8 KB
    __shared__ __align__(16) float x_lds[T_ * BT];     // [t][row], 16 KB

    for (int i = tid; i < HBUF; i += 512) ((uint32_t*)h_lds)[i] = 0u;
    for (int i = tid; i < BT * T_; i += 512) {
        const int bl = i >> 8, t = i & 255;
        x_lds[t * BT + bl] = x[(size_t)(b0 + bl) * (T_ * C_) + (size_t)t * C_ + c];
    }

    // ---- weights (pre-scaled into exp2 domain): wave w owns cols n(q)=q*128+w*16+l16
    // i,f,o scaled by -log2(e); g scaled by +2*log2(e)
    bf16x8 bw[4][4];          // [gate][k-frag] -> AGPR-resident (MFMA-only)
    AF     augb[4];           // augmented K: (wih_h, wih_l, wih_h, bias_h, bias_l, 0,0,0)
    #pragma unroll
    for (int q = 0; q < 4; ++q) {
        const float s = (q == 2) ? K2 : -K1;
        const int n = q * 128 + w * 16 + l16;
        #pragma unroll
        for (int kk = 0; kk < 4; ++kk) {
            const int k0 = kk * 32 + lg * 8;
            const float4 wa = *(const float4*)&w_hh[((size_t)(c * G_ + n)) * H_ + k0];
            const float4 wb = *(const float4*)&w_hh[((size_t)(c * G_ + n)) * H_ + k0 + 4];
            bf16x8 g;
            g[0] = (bf16_t)(s * wa.x); g[1] = (bf16_t)(s * wa.y);
            g[2] = (bf16_t)(s * wa.z); g[3] = (bf16_t)(s * wa.w);
            g[4] = (bf16_t)(s * wb.x); g[5] = (bf16_t)(s * wb.y);
            g[6] = (bf16_t)(s * wb.z); g[7] = (bf16_t)(s * wb.w);
            bw[q][kk] = g;
        }
        const float wv = s * w_ih[c * G_ + n];
        const bf16_t wh = (bf16_t)wv;
        const bf16_t wl = (bf16_t)(wv - (float)wh);
        const float bb = s * (b_ih[c * G_ + n] + b_hh[c * G_ + n]);
        const bf16_t bh  = (bf16_t)bb;
        const bf16_t bl2 = (bf16_t)(bb - (float)bh);
        bf16x8 f;
        #pragma unroll
        for (int e = 0; e < 8; ++e) f[e] = (bf16_t)0.0f;
        if (lg0) { f[0] = wh; f[1] = wl; f[2] = wh; f[3] = bh; f[4] = bl2; }
        augb[q].v = f;
    }

    float cst[4] = {0.f, 0.f, 0.f, 0.f};
    const f32x4 zc = {0.f, 0.f, 0.f, 0.f};      // shared zero C-init
    const f32x2 one2 = {1.f, 1.f};

    __syncthreads();

    // Phase stagger: the likely same-CU partner (round-robin over 8 XCDs x 32 CUs
    // => blockIdx i and i+256 share a CU) starts ~1900 cycles late so its ACT
    // phase overlaps the partner's MFMA+stall phase instead of convoying.
    if ((blockIdx.x >> 8) & 1) {
        __builtin_amdgcn_s_sleep(15);   // ~960 cyc
        __builtin_amdgcn_s_sleep(15);   // ~960 cyc
    }

    const int a_off = l16 * 8;                                          // A row = l16
    const int wbase = (w * 2 + (l16 >> 3)) * 128 + lg * 32 + (l16 & 7); // h-write base

    auto step = [&](const int RD, const int WR, const int t) {
        // augmented A: x hi/lo + bias-activators (lg0 lanes only)
        const float xr = x_lds[t * BT + l16];           // broadcast across lg
        const uint32_t p0 = cvt_pk_bf16(xr, xr);        // (xh, xh)
        const float xhf = __uint_as_float(p0 << 16);
        const uint32_t p1 = cvt_pk_bf16(xr - xhf, 1.0f); // (xl, 1.0)
        AF a4;
        a4.w[0] = lg0 ? p0 : 0u;
        a4.w[1] = lg0 ? p1 : 0u;
        a4.w[2] = lg0 ? 0x00003F80u : 0u;                // (1.0bf16, 0)
        a4.w[3] = 0u;

        f32x4 acc[4];
        #pragma unroll
        for (int q = 0; q < 4; ++q)
            acc[q] = __builtin_amdgcn_mfma_f32_16x16x32_bf16(a4.v, augb[q].v, zc, 0, 0, 0);
        #pragma unroll
        for (int kk = 0; kk < 4; ++kk) {
            const bf16x8 a = *(const bf16x8*)&h_lds[RD + (kk * 4 + lg) * 128 + a_off];
            #pragma unroll
            for (int q = 0; q < 4; ++q)
                acc[q] = __builtin_amdgcn_mfma_f32_16x16x32_bf16(a, bw[q][kk], acc[q], 0, 0, 0);
        }

        // activations, f32x2 pairs (rows 2p, 2p+1); gates already in exp2 domain
        #pragma unroll
        for (int p = 0; p < 2; ++p) {
            const f32x2 ei = exp2v(f32x2{acc[0][2*p], acc[0][2*p+1]});
            const f32x2 ef = exp2v(f32x2{acc[1][2*p], acc[1][2*p+1]});
            const f32x2 eg = exp2v(f32x2{acc[2][2*p], acc[2][2*p+1]});
            const f32x2 eo = exp2v(f32x2{acc[3][2*p], acc[3][2*p+1]});
            const f32x2 A2 = one2 + ei, D2 = one2 + ef, B2 = one2 + eg, O2 = one2 + eo;
            const f32x2 AB = A2 * B2;
            const f32x2 r1 = rcp_pair(D2 * AB);
            const f32x2 cs = {cst[2*p], cst[2*p+1]};
            const f32x2 cn = (D2 * (eg - one2) + cs * AB) * r1;
            cst[2*p] = cn.x; cst[2*p+1] = cn.y;
            f32x2 m2;
            m2.x = __builtin_amdgcn_fmed3f(K2 * cn.x, -24.f, 24.f);
            m2.y = __builtin_amdgcn_fmed3f(K2 * cn.y, -24.f, 24.f);
            const f32x2 ec = exp2v(m2);
            const f32x2 r2 = rcp_pair(O2 * (one2 + ec));
            const f32x2 hv = (ec - one2) * r2;           // sig(o)*tanh(cn)
            h_lds[WR + wbase + (2*p)   * 8] = (bf16_t)hv.x;
            h_lds[WR + wbase + (2*p+1) * 8] = (bf16_t)hv.y;
        }
        __syncthreads();
    };

    for (int t = 0; t < T_; t += 2) {
        step(0, HBUF, t);        // read buf0, write buf1
        step(HBUF, 0, t + 1);    // read buf1, write buf0
    }

    // ---- epilogue: out[b][c] = dot(h_T[b,:], w_fc[c,:]) + b_fc[c]; h_T in buf0
    #pragma unroll
    for (int rr = 0; rr < 2; ++rr) {
        const int row = w * 2 + rr;
        const int eaddr = (lane >> 2) * 128 + row * 8 + (lane & 3) * 2;  // k=2*lane
        const float h0 = (float)h_lds[eaddr];
        const float h1 = (float)h_lds[eaddr + 1];
        const float2 wf = *(const float2*)&w_fc[c * H_ + 2 * lane];
        float p = h0 * wf.x + h1 * wf.y;
        #pragma unroll
        for (int off = 32; off; off >>= 1) p += __shfl_xor(p, off);
        if (lane == 0) out[(size_t)(b0 + row) * C_ + c] = p + b_fc[c];
    }
}

extern "C" void kernel_launch(void* const* d_in, const int* in_sizes, int n_in,
                              void* d_out, int out_size, void* d_ws, size_t ws_size,
                              hipStream_t stream) {
    const float* x    = (const float*)d_in[0];
    const float* w_ih = (const float*)d_in[1];
    const float* w_hh = (const float*)d_in[2];
    const float* b_ih = (const float*)d_in[3];
    const float* b_hh = (const float*)d_in[4];
    const float* w_fc = (const float*)d_in[5];
    const float* b_fc = (const float*)d_in[6];
    float* out = (float*)d_out;

    dim3 grid(C_ * (B_ / BT));   // 512 workgroups (2/CU)
    dim3 block(512);             // 8 waves
    lstm_fused<<<grid, block, 0, stream>>>(x, w_ih, w_hh, b_ih, b_hh, w_fc, b_fc, out);
}